// Round 1
// baseline (42100.992 us; speedup 1.0000x reference)
//
#include <hip/hip_runtime.h>
#include <math.h>

#define BB 128
#define TT 512
#define II 256
#define HH 512
#define ZZ 768            // I + H
#define BH (BB*HH)        // 65536
#define NBLK 512
#define NTHR 128

__device__ __forceinline__ float sigmoidf_(float v) {
    return 1.0f / (1.0f + __expf(-v));
}

// Grid-wide barrier: monotonic counter in global memory (d_ws), zeroed by host
// memset each launch. Release fence (wbl2) before arrival so h stores reach
// LLC; acquire fence (inv) after spin so stale L2/L1 lines are dropped.
__device__ __forceinline__ void grid_barrier(unsigned int* cnt, unsigned int target) {
    __syncthreads();                       // all waves' stores drained (vmcnt) at s_barrier
    if (threadIdx.x == 0) {
        __builtin_amdgcn_fence(__ATOMIC_RELEASE, "agent");
        __hip_atomic_fetch_add(cnt, 1u, __ATOMIC_RELEASE, __HIP_MEMORY_SCOPE_AGENT);
        while (__hip_atomic_load(cnt, __ATOMIC_ACQUIRE, __HIP_MEMORY_SCOPE_AGENT) < target) {
            __builtin_amdgcn_s_sleep(2);
        }
        __builtin_amdgcn_fence(__ATOMIC_ACQUIRE, "agent");
    }
    __syncthreads();
}

__global__ __launch_bounds__(NTHR) void lstm_persistent(
    const float* __restrict__ x,
    const float* __restrict__ Wf, const float* __restrict__ bf,
    const float* __restrict__ Wu, const float* __restrict__ bu,
    const float* __restrict__ Wc, const float* __restrict__ bc,
    const float* __restrict__ Wo, const float* __restrict__ bo,
    float* __restrict__ out, unsigned int* __restrict__ cnt)
{
    // weights: [gate][local_row][k], row padded 768->772 (16B aligned, bank-spread)
    __shared__ float w_lds[4][4][772];      // 49,408 B
    // z tile: 32 batches x 64 k, row stride 68 (16B aligned), XOR-swizzled cols
    __shared__ float z_lds[32][68];         //  8,704 B   -> total 58,112 B (2 WG/CU)

    const int tid = threadIdx.x;
    const int bl  = tid & 31;               // local batch 0..31
    const int jj  = tid >> 5;               // local h-index 0..3
    const int jslice = blockIdx.x & 127;    // 128 h-slices of 4
    const int bg     = blockIdx.x >> 7;     // 4 batch groups of 32
    const int b0 = bg * 32;
    const int j0 = jslice * 4;
    const int b  = b0 + bl;
    const int j  = j0 + jj;

    // ---- stage this WG's weight rows into LDS (once) ----
    const float* Ws[4] = { Wf, Wu, Wc, Wo };
    for (int g = 0; g < 4; ++g) {
        const float* Wg = Ws[g];
        for (int r = 0; r < 4; ++r) {
            const float4* src = (const float4*)(Wg + (size_t)(j0 + r) * ZZ);
            for (int k4 = tid; k4 < ZZ / 4; k4 += NTHR) {
                float4 v = src[k4];
                *(float4*)&w_lds[g][r][k4 * 4] = v;
            }
        }
    }
    const float bias_r0 = bf[j];
    const float bias_r1 = bu[j];
    const float bias_r2 = bc[j];
    const float bias_r3 = bo[j];
    float c_reg = 0.0f;
    float h_new = 0.0f;
    __syncthreads();

    for (int t = 0; t < TT; ++t) {
        float acc0 = 0.f, acc1 = 0.f, acc2 = 0.f, acc3 = 0.f;
        const int ntile = (t == 0) ? 4 : 12;   // t=0: h is exactly zero, skip h tiles
        for (int tau = 0; tau < ntile; ++tau) {
            __syncthreads();   // previous tile's readers done before overwrite
            // stage 32 x 64 block of z = [x_t | h_{t-1}] into LDS (coalesced)
            for (int s = tid; s < 512; s += NTHR) {
                const int row = s >> 4;        // 0..31
                const int kk4 = s & 15;        // 0..15 (float4 index within 64)
                const float4* src;
                if (tau < 4) {
                    src = (const float4*)(x + ((size_t)(b0 + row) * TT + t) * II + tau * 64) + kk4;
                } else {
                    src = (const float4*)(out + (size_t)(t - 1) * BH
                                              + (size_t)(b0 + row) * HH + (tau - 4) * 64) + kk4;
                }
                float4 v = *src;
                const int col = (kk4 ^ ((row >> 2) & 3)) * 4;   // swizzle: 4-way -> 2-way banks
                *(float4*)&z_lds[row][col] = v;
            }
            __syncthreads();
            const int kw = tau * 64;
            #pragma unroll
            for (int k4 = 0; k4 < 16; ++k4) {
                const int col = (k4 ^ ((bl >> 2) & 3)) * 4;
                const float4 z  = *(const float4*)&z_lds[bl][col];
                const float4 w0 = *(const float4*)&w_lds[0][jj][kw + k4 * 4];
                const float4 w1 = *(const float4*)&w_lds[1][jj][kw + k4 * 4];
                const float4 w2 = *(const float4*)&w_lds[2][jj][kw + k4 * 4];
                const float4 w3 = *(const float4*)&w_lds[3][jj][kw + k4 * 4];
                acc0 += z.x * w0.x + z.y * w0.y + z.z * w0.z + z.w * w0.w;
                acc1 += z.x * w1.x + z.y * w1.y + z.z * w1.z + z.w * w1.w;
                acc2 += z.x * w2.x + z.y * w2.y + z.z * w2.z + z.w * w2.w;
                acc3 += z.x * w3.x + z.y * w3.y + z.z * w3.z + z.w * w3.w;
            }
        }
        // pointwise LSTM update; c stays in register across all 512 steps
        const float fg = sigmoidf_(acc0 + bias_r0);
        const float ug = sigmoidf_(acc1 + bias_r1);
        const float gg = tanhf   (acc2 + bias_r2);
        const float og = sigmoidf_(acc3 + bias_r3);
        c_reg = fg * c_reg + ug * gg;
        h_new = og * tanhf(c_reg);
        out[(size_t)t * BH + (size_t)b * HH + j] = h_new;

        grid_barrier(cnt, (unsigned int)(NBLK * (t + 1)));
    }

    // final h and c outputs
    out[(size_t)TT * BH +      (size_t)b * HH + j] = h_new;
    out[(size_t)TT * BH + BH + (size_t)b * HH + j] = c_reg;
}

extern "C" void kernel_launch(void* const* d_in, const int* in_sizes, int n_in,
                              void* d_out, int out_size, void* d_ws, size_t ws_size,
                              hipStream_t stream) {
    (void)in_sizes; (void)n_in; (void)out_size; (void)ws_size;
    const float* x  = (const float*)d_in[0];
    const float* Wf = (const float*)d_in[1];
    const float* bf = (const float*)d_in[2];
    const float* Wu = (const float*)d_in[3];
    const float* bu = (const float*)d_in[4];
    const float* Wc = (const float*)d_in[5];
    const float* bc = (const float*)d_in[6];
    const float* Wo = (const float*)d_in[7];
    const float* bo = (const float*)d_in[8];
    float* out = (float*)d_out;
    unsigned int* cnt = (unsigned int*)d_ws;

    // barrier counter must start at 0 every call (d_ws is poisoned 0xAA)
    hipMemsetAsync(d_ws, 0, 256, stream);
    lstm_persistent<<<dim3(NBLK), dim3(NTHR), 0, stream>>>(
        x, Wf, bf, Wu, bu, Wc, bc, Wo, bo, out, cnt);
}

// Round 2
// 8280.631 us; speedup vs baseline: 5.0843x; 5.0843x over previous
//
#include <hip/hip_runtime.h>
#include <math.h>

#define TT 512
#define BB 128
#define II 256
#define HH 512
#define BH (BB*HH)

#define NCLUST 8
#define BLK_PER_CL 32
#define NBLK (NCLUST*BLK_PER_CL)
#define NTHR 256

// z LDS row stride in bf16 elems: 768 data + 8 pad -> 388 dwords == 4 (mod 32)
// -> A-frag ds_read_b128 pattern matches the ideal 2-per-bank distribution.
#define ZSTR 776
#define ZBYTES (16*ZSTR*2)      // one plane: 24,832 B

typedef __bf16 bf16x8 __attribute__((ext_vector_type(8)));
typedef float  f32x4  __attribute__((ext_vector_type(4)));

// d_ws layout: [0,2048) cluster barrier counters (256B apart, memset 0)
//              [4096, 4096+524288) h-buffers: slot(2) x cluster(8) x plane(2) x 16x512 bf16
#define CNT_OFF   0
#define HBUF_OFF  4096
#define HBUF_PLANE 16384

__device__ __forceinline__ float sigf(float v)   { return 1.f / (1.f + __expf(-v)); }
__device__ __forceinline__ float tanhf_(float v) { return 2.f / (1.f + __expf(-2.f * v)) - 1.f; }

__global__ __launch_bounds__(NTHR, 1) void lstm_mfma(
    const float* __restrict__ x,
    const float* __restrict__ Wf, const float* __restrict__ bf_,
    const float* __restrict__ Wu, const float* __restrict__ bu_,
    const float* __restrict__ Wc, const float* __restrict__ bc_,
    const float* __restrict__ Wo, const float* __restrict__ bo_,
    float* __restrict__ out, char* __restrict__ ws)
{
    // z planes (hi, lo). gbuf (gate-partial exchange, 16 KB) ALIASES the start
    // of zhi: it is only live between the MFMA reads of step t and the
    // restaging for step t+1, which fully rewrites the aliased x/h regions.
    __shared__ __attribute__((aligned(16))) char smem[2*ZBYTES];
    __bf16* zhi = (__bf16*)smem;
    __bf16* zlo = (__bf16*)(smem + ZBYTES);
    float (*gbuf)[4][64][4] = (float(*)[4][64][4])smem;   // [gate][wave][lane][4]

    const int tid  = threadIdx.x;
    const int wv   = tid >> 6;           // wave 0..3 = K-split index
    const int lane = tid & 63;
    const int cluster = blockIdx.x & 7;  // XCD-locality heuristic
    const int jblk    = blockIdx.x >> 3; // 0..31
    const int j0 = jblk * 16;
    const int b0 = cluster * 16;

    unsigned int* cnt = (unsigned int*)(ws + CNT_OFF) + cluster * 64;

    const float* Ws[4] = {Wf, Wu, Wc, Wo};
    const float* Bs[4] = {bf_, bu_, bc_, bo_};

    const int n_   = lane & 15;          // B-frag n; also C/D col (j offset)
    const int quad = lane >> 4;
    const int k0   = quad * 8;

    // ---- W fragments into registers, hi/lo split: [gate][ktile] ----
    bf16x8 bhi[4][6], blo[4][6];
    #pragma unroll
    for (int g = 0; g < 4; ++g) {
        const float* wrow = Ws[g] + (size_t)(j0 + n_) * 768 + wv * 192 + k0;
        #pragma unroll
        for (int kt = 0; kt < 6; ++kt) {
            float v[8];
            *(f32x4*)&v[0] = *(const f32x4*)(wrow + kt * 32);
            *(f32x4*)&v[4] = *(const f32x4*)(wrow + kt * 32 + 4);
            bf16x8 h8, l8;
            #pragma unroll
            for (int e = 0; e < 8; ++e) {
                __bf16 hh = (__bf16)v[e];
                h8[e] = hh;
                l8[e] = (__bf16)(v[e] - (float)hh);
            }
            bhi[g][kt] = h8; blo[g][kt] = l8;
        }
    }
    float biasv[4];
    #pragma unroll
    for (int g = 0; g < 4; ++g) biasv[g] = Bs[g][j0 + n_];

    // ---- zero h-region of z (t=0 sees h=0) ----
    {
        uint4 zz; zz.x = zz.y = zz.z = zz.w = 0u;
        #pragma unroll
        for (int i = 0; i < 4; ++i) {
            int c = tid + 256 * i;          // 1024 chunks of 16B per plane
            int row = c >> 6, cc = c & 63;
            *(uint4*)&zhi[row * ZSTR + 256 + cc * 8] = zz;
            *(uint4*)&zlo[row * ZSTR + 256 + cc * 8] = zz;
        }
    }

    auto stage_x = [&](int t) {
        #pragma unroll
        for (int i = 0; i < 2; ++i) {
            int c = tid + 256 * i;          // 512 chunks (8 floats each)
            int row = c >> 5, cc = c & 31;
            const float* p = x + (size_t)(b0 + row) * (TT * II) + (size_t)t * II + cc * 8;
            float v[8];
            *(f32x4*)&v[0] = *(const f32x4*)p;
            *(f32x4*)&v[4] = *(const f32x4*)(p + 4);
            bf16x8 h8, l8;
            #pragma unroll
            for (int e = 0; e < 8; ++e) {
                __bf16 hh = (__bf16)v[e];
                h8[e] = hh;
                l8[e] = (__bf16)(v[e] - (float)hh);
            }
            *(bf16x8*)&zhi[row * ZSTR + cc * 8] = h8;
            *(bf16x8*)&zlo[row * ZSTR + cc * 8] = l8;
        }
    };

    auto stage_h = [&](int slot) {
        const uint4* sh = (const uint4*)(ws + HBUF_OFF + (size_t)((slot * 8 + cluster) * 2 + 0) * HBUF_PLANE);
        const uint4* sl = (const uint4*)(ws + HBUF_OFF + (size_t)((slot * 8 + cluster) * 2 + 1) * HBUF_PLANE);
        #pragma unroll
        for (int i = 0; i < 4; ++i) {
            int c = tid + 256 * i;          // 1024 16B-chunks per plane
            int row = c >> 6, cc = c & 63;
            uint4 vh = sh[c];
            uint4 vl = sl[c];
            *(uint4*)&zhi[row * ZSTR + 256 + cc * 8] = vh;
            *(uint4*)&zlo[row * ZSTR + 256 + cc * 8] = vl;
        }
    };

    stage_x(0);

    f32x4 cfr = {0.f, 0.f, 0.f, 0.f};
    f32x4 hfr = {0.f, 0.f, 0.f, 0.f};

    const __bf16* zh_row = &zhi[n_ * ZSTR + wv * 192 + k0];   // A-frag m = lane&15
    const __bf16* zl_row = &zlo[n_ * ZSTR + wv * 192 + k0];

    for (int t = 0; t < TT; ++t) {
        if (t > 0) {
            if (tid == 0) {
                while (__hip_atomic_load(cnt, __ATOMIC_ACQUIRE, __HIP_MEMORY_SCOPE_AGENT)
                       < (unsigned int)(BLK_PER_CL * t)) {
                    __builtin_amdgcn_s_sleep(1);
                }
                __builtin_amdgcn_fence(__ATOMIC_ACQUIRE, "agent");
            }
            __syncthreads();
            stage_h((t - 1) & 1);
        }
        __syncthreads();   // staging (x and h) visible to all waves

        // ---- K-split MFMA: this wave covers K in [wv*192, wv*192+192) for all gates ----
        f32x4 acc[4][3];
        #pragma unroll
        for (int g = 0; g < 4; ++g)
            #pragma unroll
            for (int s = 0; s < 3; ++s)
                acc[g][s] = (f32x4){0.f, 0.f, 0.f, 0.f};

        #pragma unroll
        for (int kt = 0; kt < 6; ++kt) {
            bf16x8 ah = *(const bf16x8*)(zh_row + kt * 32);
            bf16x8 al = *(const bf16x8*)(zl_row + kt * 32);
            #pragma unroll
            for (int g = 0; g < 4; ++g) {
                acc[g][0] = __builtin_amdgcn_mfma_f32_16x16x32_bf16(ah, bhi[g][kt], acc[g][0], 0, 0, 0);
                acc[g][1] = __builtin_amdgcn_mfma_f32_16x16x32_bf16(ah, blo[g][kt], acc[g][1], 0, 0, 0);
                acc[g][2] = __builtin_amdgcn_mfma_f32_16x16x32_bf16(al, bhi[g][kt], acc[g][2], 0, 0, 0);
            }
        }
        __syncthreads();   // all z reads done before gbuf aliases over zhi
        #pragma unroll
        for (int g = 0; g < 4; ++g) {
            f32x4 pre = acc[g][0] + acc[g][1] + acc[g][2];
            *(f32x4*)&gbuf[g][wv][lane][0] = pre;
        }
        __syncthreads();

        if (wv == 0) {
            f32x4 s[4];
            #pragma unroll
            for (int g = 0; g < 4; ++g) {
                f32x4 t0 = *(const f32x4*)&gbuf[g][0][lane][0];
                f32x4 t1 = *(const f32x4*)&gbuf[g][1][lane][0];
                f32x4 t2 = *(const f32x4*)&gbuf[g][2][lane][0];
                f32x4 t3 = *(const f32x4*)&gbuf[g][3][lane][0];
                s[g] = (t0 + t1) + (t2 + t3) + biasv[g];
            }
            __bf16* dh = (__bf16*)(ws + HBUF_OFF + (size_t)(((t & 1) * 8 + cluster) * 2 + 0) * HBUF_PLANE);
            __bf16* dl = (__bf16*)(ws + HBUF_OFF + (size_t)(((t & 1) * 8 + cluster) * 2 + 1) * HBUF_PLANE);
            #pragma unroll
            for (int e = 0; e < 4; ++e) {
                float f  = sigf(s[0][e]);
                float u  = sigf(s[1][e]);
                float g2 = tanhf_(s[2][e]);
                float o  = sigf(s[3][e]);
                cfr[e] = f * cfr[e] + u * g2;
                float hv = o * tanhf_(cfr[e]);
                hfr[e] = hv;
                int row = quad * 4 + e;                   // C/D: row = (lane>>4)*4 + reg
                out[(size_t)t * BH + (size_t)(b0 + row) * HH + j0 + n_] = hv;
                __bf16 hh = (__bf16)hv;
                dh[row * HH + j0 + n_] = hh;
                dl[row * HH + j0 + n_] = (__bf16)(hv - (float)hh);
            }
        }
        __syncthreads();   // wave0's h stores drained (vmcnt0 at barrier)

        if (t < TT - 1) {
            if (tid == 0) {
                __builtin_amdgcn_fence(__ATOMIC_RELEASE, "agent");
                __hip_atomic_fetch_add(cnt, 1u, __ATOMIC_RELEASE, __HIP_MEMORY_SCOPE_AGENT);
            }
            stage_x(t + 1);   // overlaps the other blocks' spins
        }
    }

    if (wv == 0) {
        #pragma unroll
        for (int e = 0; e < 4; ++e) {
            int row = quad * 4 + e;
            out[(size_t)TT * BH +      (size_t)(b0 + row) * HH + j0 + n_] = hfr[e];
            out[(size_t)TT * BH + BH + (size_t)(b0 + row) * HH + j0 + n_] = cfr[e];
        }
    }
}

extern "C" void kernel_launch(void* const* d_in, const int* in_sizes, int n_in,
                              void* d_out, int out_size, void* d_ws, size_t ws_size,
                              hipStream_t stream) {
    (void)in_sizes; (void)n_in; (void)out_size; (void)ws_size;
    const float* x  = (const float*)d_in[0];
    const float* Wf = (const float*)d_in[1];
    const float* bf = (const float*)d_in[2];
    const float* Wu = (const float*)d_in[3];
    const float* bu = (const float*)d_in[4];
    const float* Wc = (const float*)d_in[5];
    const float* bc = (const float*)d_in[6];
    const float* Wo = (const float*)d_in[7];
    const float* bo = (const float*)d_in[8];

    hipMemsetAsync((char*)d_ws + CNT_OFF, 0, 2048, stream);
    lstm_mfma<<<dim3(NBLK), dim3(NTHR), 0, stream>>>(
        x, Wf, bf, Wu, bu, Wc, bc, Wo, bo, (float*)d_out, (char*)d_ws);
}

// Round 3
// 5483.300 us; speedup vs baseline: 7.6780x; 1.5102x over previous
//
#include <hip/hip_runtime.h>
#include <math.h>

#define TT 512
#define BB 128
#define II 256
#define HH 512
#define BH (BB*HH)

#define NCLUST 8
#define BLK_PER_CL 32
#define NBLK 256
#define NTHR 256

// x LDS row stride (bf16): 256 + 8 pad -> 132 dwords == 4 (mod 32) -> 2-way max
#define XSTR 264
#define CNT_OFF 0
#define HBUF_OFF 4096
#define HBUF_PLANE 16384   // one plane: 16 rows x 512 cols bf16

typedef __bf16 bf16x8 __attribute__((ext_vector_type(8)));
typedef float  f32x4  __attribute__((ext_vector_type(4)));

__device__ __forceinline__ float sigf(float v)   { return 1.f / (1.f + __expf(-v)); }
__device__ __forceinline__ float tanhf_(float v) { return 2.f / (1.f + __expf(-2.f * v)) - 1.f; }

__device__ __forceinline__ void split8(const float* p, bf16x8& h8, bf16x8& l8) {
    f32x4 a = *(const f32x4*)p;
    f32x4 b = *(const f32x4*)(p + 4);
    float v[8] = {a[0], a[1], a[2], a[3], b[0], b[1], b[2], b[3]};
    #pragma unroll
    for (int e = 0; e < 8; ++e) {
        __bf16 hh = (__bf16)v[e];
        h8[e] = hh;
        l8[e] = (__bf16)(v[e] - (float)hh);
    }
}

__global__ __launch_bounds__(NTHR, 1) void lstm_mfma2(
    const float* __restrict__ x,
    const float* __restrict__ Wf, const float* __restrict__ bf_,
    const float* __restrict__ Wu, const float* __restrict__ bu_,
    const float* __restrict__ Wc, const float* __restrict__ bc_,
    const float* __restrict__ Wo, const float* __restrict__ bo_,
    float* __restrict__ out, char* __restrict__ ws)
{
    __shared__ __attribute__((aligned(16))) __bf16 xhi[16 * XSTR];
    __shared__ __attribute__((aligned(16))) __bf16 xlo[16 * XSTR];
    __shared__ __attribute__((aligned(16))) float  gbuf[16][64][4];   // [g*4+wv][lane][4]

    const int tid  = threadIdx.x;
    const int wv   = tid >> 6;
    const int lane = tid & 63;
    const int cluster = blockIdx.x & 7;
    const int jblk    = blockIdx.x >> 3;      // 0..31 within cluster
    const int j0 = jblk * 16;
    const int b0 = cluster * 16;
    const int n_ = lane & 15, quad = lane >> 4, k0 = quad * 8;

    unsigned* flags = (unsigned*)(ws + CNT_OFF) + cluster * 128;   // 32 flags, 16B apart

    const float* Ws[4] = {Wf, Wu, Wc, Wo};
    const float* Bs[4] = {bf_, bu_, bc_, bo_};

    // W fragments in registers. Wave wv owns z-K: x[wv*64,+64) and h[wv*128,+128)
    bf16x8 bxh[4][2], bxl[4][2], bhh[4][4], bhl[4][4];
    #pragma unroll
    for (int g = 0; g < 4; ++g) {
        const float* wr = Ws[g] + (size_t)(j0 + n_) * 768;
        #pragma unroll
        for (int kt = 0; kt < 2; ++kt)
            split8(wr + wv * 64 + kt * 32 + k0, bxh[g][kt], bxl[g][kt]);
        #pragma unroll
        for (int kt = 0; kt < 4; ++kt)
            split8(wr + 256 + wv * 128 + kt * 32 + k0, bhh[g][kt], bhl[g][kt]);
    }
    float biasv[4];
    #pragma unroll
    for (int g = 0; g < 4; ++g) biasv[g] = Bs[g][j0 + n_];

    auto stage_x = [&](int t, int base, int stride) {
        for (int c = base; c < 1024; c += stride) {       // 16 rows x 64 float4-chunks
            const int row = c >> 6, cc = c & 63;
            const float* p = x + (size_t)(b0 + row) * (TT * II) + (size_t)t * II + cc * 4;
            f32x4 v = *(const f32x4*)p;
            __bf16 h4[4], l4[4];
            #pragma unroll
            for (int e = 0; e < 4; ++e) {
                __bf16 hh = (__bf16)v[e];
                h4[e] = hh;
                l4[e] = (__bf16)(v[e] - (float)hh);
            }
            *(uint2*)&xhi[row * XSTR + cc * 4] = *(uint2*)h4;
            *(uint2*)&xlo[row * XSTR + cc * 4] = *(uint2*)l4;
        }
    };

    stage_x(0, tid, NTHR);
    __syncthreads();

    f32x4 cfr = {0.f, 0.f, 0.f, 0.f};
    f32x4 hfr = {0.f, 0.f, 0.f, 0.f};

    for (int t = 0; t < TT; ++t) {
        f32x4 acc[4][3];
        #pragma unroll
        for (int g = 0; g < 4; ++g)
            #pragma unroll
            for (int s = 0; s < 3; ++s)
                acc[g][s] = (f32x4){0.f, 0.f, 0.f, 0.f};

        // ---- phase A: x-contribution (LDS, staged last step) ----
        #pragma unroll
        for (int kt = 0; kt < 2; ++kt) {
            bf16x8 ah = *(const bf16x8*)&xhi[n_ * XSTR + wv * 64 + kt * 32 + k0];
            bf16x8 al = *(const bf16x8*)&xlo[n_ * XSTR + wv * 64 + kt * 32 + k0];
            #pragma unroll
            for (int g = 0; g < 4; ++g) {
                acc[g][0] = __builtin_amdgcn_mfma_f32_16x16x32_bf16(ah, bxh[g][kt], acc[g][0], 0, 0, 0);
                acc[g][1] = __builtin_amdgcn_mfma_f32_16x16x32_bf16(ah, bxl[g][kt], acc[g][1], 0, 0, 0);
                acc[g][2] = __builtin_amdgcn_mfma_f32_16x16x32_bf16(al, bxh[g][kt], acc[g][2], 0, 0, 0);
            }
        }

        // ---- wait for h(t-1), then phase C: h-contribution (direct global frags) ----
        if (t > 0) {
            if (wv == 0) {
                const unsigned tgt = (unsigned)t;
                const unsigned* fp = flags + (lane & 31) * 4;
                while (true) {
                    unsigned v = tgt;
                    if (lane < 32)
                        v = __hip_atomic_load(fp, __ATOMIC_RELAXED, __HIP_MEMORY_SCOPE_AGENT);
                    if (__all((int)(v >= tgt))) break;
                    __builtin_amdgcn_s_sleep(1);
                }
                __builtin_amdgcn_fence(__ATOMIC_ACQUIRE, "agent");
            }
            __syncthreads();
            const size_t base = HBUF_OFF + (size_t)((((t - 1) & 1) * 8 + cluster) * 2) * HBUF_PLANE;
            const __bf16* hp = (const __bf16*)(ws + base);
            const __bf16* lp = (const __bf16*)(ws + base + HBUF_PLANE);
            const int off = n_ * HH + wv * 128 + k0;
            #pragma unroll
            for (int kt = 0; kt < 4; ++kt) {
                bf16x8 ah = *(const bf16x8*)(hp + off + kt * 32);
                bf16x8 al = *(const bf16x8*)(lp + off + kt * 32);
                #pragma unroll
                for (int g = 0; g < 4; ++g) {
                    acc[g][0] = __builtin_amdgcn_mfma_f32_16x16x32_bf16(ah, bhh[g][kt], acc[g][0], 0, 0, 0);
                    acc[g][1] = __builtin_amdgcn_mfma_f32_16x16x32_bf16(ah, bhl[g][kt], acc[g][1], 0, 0, 0);
                    acc[g][2] = __builtin_amdgcn_mfma_f32_16x16x32_bf16(al, bhh[g][kt], acc[g][2], 0, 0, 0);
                }
            }
        }

        // ---- cross-wave K reduction through LDS ----
        #pragma unroll
        for (int g = 0; g < 4; ++g) {
            f32x4 pre = acc[g][0] + acc[g][1] + acc[g][2];
            *(f32x4*)&gbuf[g * 4 + wv][lane][0] = pre;
        }
        __syncthreads();

        if (wv == 0) {
            f32x4 s[4];
            #pragma unroll
            for (int g = 0; g < 4; ++g) {
                f32x4 t0 = *(const f32x4*)&gbuf[g * 4 + 0][lane][0];
                f32x4 t1 = *(const f32x4*)&gbuf[g * 4 + 1][lane][0];
                f32x4 t2 = *(const f32x4*)&gbuf[g * 4 + 2][lane][0];
                f32x4 t3 = *(const f32x4*)&gbuf[g * 4 + 3][lane][0];
                s[g] = (t0 + t1) + (t2 + t3) + biasv[g];
            }
            const size_t dbase = HBUF_OFF + (size_t)(((t & 1) * 8 + cluster) * 2) * HBUF_PLANE;
            __bf16* dh = (__bf16*)(ws + dbase);
            __bf16* dl = (__bf16*)(ws + dbase + HBUF_PLANE);
            #pragma unroll
            for (int e = 0; e < 4; ++e) {
                float f  = sigf(s[0][e]);
                float u  = sigf(s[1][e]);
                float g2 = tanhf_(s[2][e]);
                float o  = sigf(s[3][e]);
                cfr[e] = f * cfr[e] + u * g2;
                float hv = o * tanhf_(cfr[e]);
                hfr[e] = hv;
                const int row = quad * 4 + e;
                out[(size_t)t * BH + (size_t)(b0 + row) * HH + j0 + n_] = hv;
                if (t < TT - 1) {
                    __bf16 hh = (__bf16)hv;
                    dh[row * HH + j0 + n_] = hh;
                    dl[row * HH + j0 + n_] = (__bf16)(hv - (float)hh);
                }
            }
            if (t < TT - 1 && tid == 0) {
                // release store: drains wave0's h stores + L2 writeback, then flag
                __hip_atomic_store(flags + jblk * 4, (unsigned)(t + 1),
                                   __ATOMIC_RELEASE, __HIP_MEMORY_SCOPE_AGENT);
            }
        } else if (t < TT - 1) {
            stage_x(t + 1, tid - 64, 192);   // waves 1-3 stage next x during publish
        }
        __syncthreads();
    }

    if (wv == 0) {
        #pragma unroll
        for (int e = 0; e < 4; ++e) {
            const int row = quad * 4 + e;
            out[(size_t)TT * BH +      (size_t)(b0 + row) * HH + j0 + n_] = hfr[e];
            out[(size_t)TT * BH + BH + (size_t)(b0 + row) * HH + j0 + n_] = cfr[e];
        }
    }
}

extern "C" void kernel_launch(void* const* d_in, const int* in_sizes, int n_in,
                              void* d_out, int out_size, void* d_ws, size_t ws_size,
                              hipStream_t stream) {
    (void)in_sizes; (void)n_in; (void)out_size; (void)ws_size;
    const float* x  = (const float*)d_in[0];
    const float* Wf = (const float*)d_in[1];
    const float* bf = (const float*)d_in[2];
    const float* Wu = (const float*)d_in[3];
    const float* bu = (const float*)d_in[4];
    const float* Wc = (const float*)d_in[5];
    const float* bc = (const float*)d_in[6];
    const float* Wo = (const float*)d_in[7];
    const float* bo = (const float*)d_in[8];

    hipMemsetAsync((char*)d_ws + CNT_OFF, 0, 4096, stream);
    lstm_mfma2<<<dim3(NBLK), dim3(NTHR), 0, stream>>>(
        x, Wf, bf, Wu, bu, Wc, bc, Wo, bo, (float*)d_out, (char*)d_ws);
}

// Round 4
// 2968.504 us; speedup vs baseline: 14.1826x; 1.8472x over previous
//
#include <hip/hip_runtime.h>
#include <math.h>

#define TT 512
#define BB 128
#define II 256
#define HH 512
#define BH (BB*HH)

#define NCLUST 8
#define BLK_PER_CL 32
#define NBLK 256
#define NTHR 256

// x LDS row stride (bf16): 256 + 8 pad -> 132 dwords == 4 (mod 32) -> 2-way max
#define XSTR 264
#define FLAG_OFF 0          // 8 clusters x 32 flags x 16B = 4096
#define XCC_OFF  4096       // 8 clusters x 32 x 4B = 1024
#define HBUF_OFF 8192
#define HBUF_PLANE 16384    // one plane: 16 rows x 512 cols bf16

typedef __bf16 bf16x8 __attribute__((ext_vector_type(8)));
typedef float  f32x4  __attribute__((ext_vector_type(4)));
typedef unsigned long long u64;

__device__ __forceinline__ float sigf(float v)   { return 1.f / (1.f + __expf(-v)); }
__device__ __forceinline__ float tanhf_(float v) { return 2.f / (1.f + __expf(-2.f * v)) - 1.f; }

__device__ __forceinline__ void split8(const float* p, bf16x8& h8, bf16x8& l8) {
    f32x4 a = *(const f32x4*)p;
    f32x4 b = *(const f32x4*)(p + 4);
    float v[8] = {a[0], a[1], a[2], a[3], b[0], b[1], b[2], b[3]};
    #pragma unroll
    for (int e = 0; e < 8; ++e) {
        __bf16 hh = (__bf16)v[e];
        h8[e] = hh;
        l8[e] = (__bf16)(v[e] - (float)hh);
    }
}

// 16B fragment load from the h-planes: two 8B relaxed agent-scope atomic loads
// -> global_load_dwordx2 with sc0 (L1 bypass) -> always reads the XCD-L2 copy.
__device__ __forceinline__ bf16x8 load_frag_sc0(const __bf16* p) {
    union { u64 q[2]; bf16x8 v; } u;
    const u64* qp = (const u64*)p;
    u.q[0] = __hip_atomic_load(qp,     __ATOMIC_RELAXED, __HIP_MEMORY_SCOPE_AGENT);
    u.q[1] = __hip_atomic_load(qp + 1, __ATOMIC_RELAXED, __HIP_MEMORY_SCOPE_AGENT);
    return u.v;
}

__global__ __launch_bounds__(NTHR, 1) void lstm_mfma3(
    const float* __restrict__ x,
    const float* __restrict__ Wf, const float* __restrict__ bf_,
    const float* __restrict__ Wu, const float* __restrict__ bu_,
    const float* __restrict__ Wc, const float* __restrict__ bc_,
    const float* __restrict__ Wo, const float* __restrict__ bo_,
    float* __restrict__ out, char* __restrict__ ws)
{
    __shared__ __attribute__((aligned(16))) __bf16 xhi[16 * XSTR];
    __shared__ __attribute__((aligned(16))) __bf16 xlo[16 * XSTR];
    __shared__ __attribute__((aligned(16))) float  gbuf[16][64][4];   // [g*4+wv][lane][4]

    const int tid  = threadIdx.x;
    const int wv   = tid >> 6;
    const int lane = tid & 63;
    const int cluster = blockIdx.x & 7;       // same-XCD under %8 round-robin
    const int jblk    = blockIdx.x >> 3;      // 0..31 within cluster
    const int j0 = jblk * 16;
    const int b0 = cluster * 16;
    const int n_ = lane & 15, quad = lane >> 4, k0 = quad * 8;

    unsigned* flags = (unsigned*)(ws + FLAG_OFF) + cluster * 128;   // 32 flags, 16B apart
    unsigned* xccp  = (unsigned*)(ws + XCC_OFF)  + cluster * 32;

    // ---- XCD handshake: publish my XCC_ID, check the whole cluster matches ----
    const unsigned myxcc = __builtin_amdgcn_s_getreg((3 << 11) | 20);  // hwreg(XCC_ID,0,4)
    if (tid == 0)
        __hip_atomic_store(xccp + jblk, 0x100u | myxcc,
                           __ATOMIC_RELAXED, __HIP_MEMORY_SCOPE_AGENT);

    const float* Ws[4] = {Wf, Wu, Wc, Wo};
    const float* Bs[4] = {bf_, bu_, bc_, bo_};

    // W fragments in registers. Wave wv owns z-K: x[wv*64,+64) and h[wv*128,+128)
    bf16x8 bxh[4][2], bxl[4][2], bhh[4][4], bhl[4][4];
    #pragma unroll
    for (int g = 0; g < 4; ++g) {
        const float* wr = Ws[g] + (size_t)(j0 + n_) * 768;
        #pragma unroll
        for (int kt = 0; kt < 2; ++kt)
            split8(wr + wv * 64 + kt * 32 + k0, bxh[g][kt], bxl[g][kt]);
        #pragma unroll
        for (int kt = 0; kt < 4; ++kt)
            split8(wr + 256 + wv * 128 + kt * 32 + k0, bhh[g][kt], bhl[g][kt]);
    }
    float biasv[4];
    #pragma unroll
    for (int g = 0; g < 4; ++g) biasv[g] = Bs[g][j0 + n_];

    auto stage_x = [&](int t, int base, int stride) {
        for (int c = base; c < 1024; c += stride) {       // 16 rows x 64 float4-chunks
            const int row = c >> 6, cc = c & 63;
            const float* p = x + (size_t)(b0 + row) * (TT * II) + (size_t)t * II + cc * 4;
            f32x4 v = *(const f32x4*)p;
            __bf16 h4[4], l4[4];
            #pragma unroll
            for (int e = 0; e < 4; ++e) {
                __bf16 hh = (__bf16)v[e];
                h4[e] = hh;
                l4[e] = (__bf16)(v[e] - (float)hh);
            }
            *(uint2*)&xhi[row * XSTR + cc * 4] = *(uint2*)h4;
            *(uint2*)&xlo[row * XSTR + cc * 4] = *(uint2*)l4;
        }
    };

    stage_x(0, tid, NTHR);

    // finish handshake (overlapped with W/x staging above)
    bool fast;
    {
        const unsigned mine = 0x100u | myxcc;
        while (true) {
            unsigned w = mine;
            if (lane < 32)
                w = __hip_atomic_load(xccp + lane, __ATOMIC_RELAXED, __HIP_MEMORY_SCOPE_AGENT);
            if (__all((int)(w >= 0x100u))) {
                fast = (bool)__all((int)(w == mine));
                break;
            }
            __builtin_amdgcn_s_sleep(2);
        }
    }
    __syncthreads();

    f32x4 cfr = {0.f, 0.f, 0.f, 0.f};
    f32x4 hfr = {0.f, 0.f, 0.f, 0.f};

    for (int t = 0; t < TT; ++t) {
        f32x4 acc[4][3];
        #pragma unroll
        for (int g = 0; g < 4; ++g)
            #pragma unroll
            for (int s = 0; s < 3; ++s)
                acc[g][s] = (f32x4){0.f, 0.f, 0.f, 0.f};

        // ---- phase A: x-contribution (LDS, staged last step) ----
        #pragma unroll
        for (int kt = 0; kt < 2; ++kt) {
            bf16x8 ah = *(const bf16x8*)&xhi[n_ * XSTR + wv * 64 + kt * 32 + k0];
            bf16x8 al = *(const bf16x8*)&xlo[n_ * XSTR + wv * 64 + kt * 32 + k0];
            #pragma unroll
            for (int g = 0; g < 4; ++g) {
                acc[g][0] = __builtin_amdgcn_mfma_f32_16x16x32_bf16(ah, bxh[g][kt], acc[g][0], 0, 0, 0);
                acc[g][1] = __builtin_amdgcn_mfma_f32_16x16x32_bf16(ah, bxl[g][kt], acc[g][1], 0, 0, 0);
                acc[g][2] = __builtin_amdgcn_mfma_f32_16x16x32_bf16(al, bxh[g][kt], acc[g][2], 0, 0, 0);
            }
        }

        // ---- per-wave wait for this wave's 8 producers, then phase C ----
        if (t > 0) {
            const unsigned tgt = (unsigned)t;
            const unsigned* fp = flags + (wv * 8 + (lane & 7)) * 4;
            while (true) {
                unsigned v = tgt;
                if (lane < 8)
                    v = __hip_atomic_load(fp, __ATOMIC_RELAXED, __HIP_MEMORY_SCOPE_AGENT);
                if (__all((int)(v >= tgt))) break;
                __builtin_amdgcn_s_sleep(1);
            }
            if (!fast) __builtin_amdgcn_fence(__ATOMIC_ACQUIRE, "agent");
            else       asm volatile("" ::: "memory");   // compiler barrier only

            const size_t base = HBUF_OFF + (size_t)((((t - 1) & 1) * 8 + cluster) * 2) * HBUF_PLANE;
            const __bf16* hp = (const __bf16*)(ws + base);
            const __bf16* lp = (const __bf16*)(ws + base + HBUF_PLANE);
            const int off = n_ * HH + wv * 128 + k0;
            #pragma unroll
            for (int kt = 0; kt < 4; ++kt) {
                bf16x8 ah = load_frag_sc0(hp + off + kt * 32);
                bf16x8 al = load_frag_sc0(lp + off + kt * 32);
                #pragma unroll
                for (int g = 0; g < 4; ++g) {
                    acc[g][0] = __builtin_amdgcn_mfma_f32_16x16x32_bf16(ah, bhh[g][kt], acc[g][0], 0, 0, 0);
                    acc[g][1] = __builtin_amdgcn_mfma_f32_16x16x32_bf16(ah, bhl[g][kt], acc[g][1], 0, 0, 0);
                    acc[g][2] = __builtin_amdgcn_mfma_f32_16x16x32_bf16(al, bhh[g][kt], acc[g][2], 0, 0, 0);
                }
            }
        }

        // ---- cross-wave K reduction through LDS ----
        #pragma unroll
        for (int g = 0; g < 4; ++g) {
            f32x4 pre = acc[g][0] + acc[g][1] + acc[g][2];
            *(f32x4*)&gbuf[g * 4 + wv][lane][0] = pre;
        }
        __syncthreads();

        if (wv == 0) {
            f32x4 s[4];
            #pragma unroll
            for (int g = 0; g < 4; ++g) {
                f32x4 t0 = *(const f32x4*)&gbuf[g * 4 + 0][lane][0];
                f32x4 t1 = *(const f32x4*)&gbuf[g * 4 + 1][lane][0];
                f32x4 t2 = *(const f32x4*)&gbuf[g * 4 + 2][lane][0];
                f32x4 t3 = *(const f32x4*)&gbuf[g * 4 + 3][lane][0];
                s[g] = (t0 + t1) + (t2 + t3) + biasv[g];
            }
            float hv4[4];
            #pragma unroll
            for (int e = 0; e < 4; ++e) {
                float f  = sigf(s[0][e]);
                float u  = sigf(s[1][e]);
                float g2 = tanhf_(s[2][e]);
                float o  = sigf(s[3][e]);
                cfr[e] = f * cfr[e] + u * g2;
                float hv = o * tanhf_(cfr[e]);
                hfr[e] = hv;
                hv4[e] = hv;
            }
            if (t < TT - 1) {
                const size_t dbase = HBUF_OFF + (size_t)(((t & 1) * 8 + cluster) * 2) * HBUF_PLANE;
                __bf16* dh = (__bf16*)(ws + dbase);
                __bf16* dl = (__bf16*)(ws + dbase + HBUF_PLANE);
                #pragma unroll
                for (int e = 0; e < 4; ++e) {
                    const int row = quad * 4 + e;
                    __bf16 hh = (__bf16)hv4[e];
                    dh[row * HH + j0 + n_] = hh;
                    dl[row * HH + j0 + n_] = (__bf16)(hv4[e] - (float)hh);
                }
                // publish: drain h stores to L2, then flag. No L2 writeback in fast mode.
                asm volatile("s_waitcnt vmcnt(0)" ::: "memory");
                if (!fast) __builtin_amdgcn_fence(__ATOMIC_RELEASE, "agent");
                if (tid == 0)
                    __hip_atomic_store(flags + jblk * 4, (unsigned)(t + 1),
                                       __ATOMIC_RELAXED, __HIP_MEMORY_SCOPE_AGENT);
            }
            // fp32 output stores AFTER the flag: off the serial path
            #pragma unroll
            for (int e = 0; e < 4; ++e) {
                const int row = quad * 4 + e;
                out[(size_t)t * BH + (size_t)(b0 + row) * HH + j0 + n_] = hv4[e];
            }
        } else if (t < TT - 1) {
            stage_x(t + 1, tid - 64, 192);   // waves 1-3 stage next x during publish
        }
        __syncthreads();
    }

    if (wv == 0) {
        #pragma unroll
        for (int e = 0; e < 4; ++e) {
            const int row = quad * 4 + e;
            out[(size_t)TT * BH +      (size_t)(b0 + row) * HH + j0 + n_] = hfr[e];
            out[(size_t)TT * BH + BH + (size_t)(b0 + row) * HH + j0 + n_] = cfr[e];
        }
    }
}

extern "C" void kernel_launch(void* const* d_in, const int* in_sizes, int n_in,
                              void* d_out, int out_size, void* d_ws, size_t ws_size,
                              hipStream_t stream) {
    (void)in_sizes; (void)n_in; (void)out_size; (void)ws_size;
    const float* x  = (const float*)d_in[0];
    const float* Wf = (const float*)d_in[1];
    const float* bf = (const float*)d_in[2];
    const float* Wu = (const float*)d_in[3];
    const float* bu = (const float*)d_in[4];
    const float* Wc = (const float*)d_in[5];
    const float* bc = (const float*)d_in[6];
    const float* Wo = (const float*)d_in[7];
    const float* bo = (const float*)d_in[8];

    hipMemsetAsync(d_ws, 0, 8192, stream);   // flags + xcc handshake area
    lstm_mfma3<<<dim3(NBLK), dim3(NTHR), 0, stream>>>(
        x, Wf, bf, Wu, bu, Wc, bc, Wo, bo, (float*)d_out, (char*)d_ws);
}